// Round 11
// baseline (131.970 us; speedup 1.0000x reference)
//
#include <hip/hip_runtime.h>
#include <math.h>

// GaussianKDE: out[i] = (1/N) * sum_j exp(x_i.y_j - 0.5||x_i||^2 - 0.5||y_j||^2 - 16*ln(2pi))
// N = M = 16384, D = 32, f32 in/out.
//
// R11 = R10 body unchanged; residency push only:
//   1. SPLITS 32->64 (4096 blocks = 16 blocks/CU, 2x oversubscription)
//   2. __launch_bounds__(256,8) (VGPR=40 << 64 cap; R3's lb-suspicion was
//      disproven by R6 -- the asm exp was the bug)
// Ledger (R10, kde_mfma 40us): VALU 21.8 (trans 13.7 floor + adds 3.4 + misc),
// MFMA 6.2, stall ~12. Occupancy stuck 31-40% across R4-R10 -> ~3 waves/SIMD;
// this round targets the stall term via true residency.

#define D 32
#define BLOCK 256
#define WAVES 4
#define WT 4                       // 16-row i-tiles per wave
#define ROWS_PER_WAVE (WT * 16)    // 64
#define ROWS_PER_BLOCK (WAVES * ROWS_PER_WAVE)  // 256
#define SPLITS 64

#define LOG2E 1.4426950408889634f
#define SQRT_LOG2E 1.2011224087864498f

typedef __attribute__((ext_vector_type(8))) _Float16 f16x8;
typedef __attribute__((ext_vector_type(4))) float f32x4;

static __device__ __forceinline__ float fast_exp2(float x) {
    return __builtin_amdgcn_exp2f(x);   // v_exp_f32, compiler-visible (R6 fix)
}

#define MFMA16F(A, B, C) __builtin_amdgcn_mfma_f32_16x16x32_f16((A), (B), (C), 0, 0, 0)

// ---- precompute X: f16 round of sqrt(log2e)-scaled rows + cx ----------------
__global__ void cvt_x(const float* __restrict__ src, _Float16* __restrict__ hi,
                      float* __restrict__ cx, int rows)
{
    int r = blockIdx.x * blockDim.x + threadIdx.x;
    if (r >= rows) return;
    const float4* p = (const float4*)(src + (size_t)r * D);
    float v[D];
    float nrm = 0.f;
#pragma unroll
    for (int q = 0; q < D / 4; ++q) {
        float4 f = p[q];
        v[q * 4 + 0] = f.x; v[q * 4 + 1] = f.y; v[q * 4 + 2] = f.z; v[q * 4 + 3] = f.w;
        nrm += f.x * f.x + f.y * f.y + f.z * f.z + f.w * f.w;
    }
    cx[r] = -0.5f * LOG2E * nrm;                 // exact f32 norm
    _Float16 hb[D];
#pragma unroll
    for (int k = 0; k < D; ++k)
        hb[k] = (_Float16)(v[k] * SQRT_LOG2E);   // RNE
    f16x8* ho = (f16x8*)(hi + (size_t)r * D);
#pragma unroll
    for (int q = 0; q < D / 8; ++q) {
        f16x8 a;
#pragma unroll
        for (int e = 0; e < 8; ++e) a[e] = hb[q * 8 + e];
        ho[q] = a;
    }
}

// ---- precompute Y: f16 round of scaled rows + cy (log2-domain const) --------
__global__ void cvt_y(const float* __restrict__ src, _Float16* __restrict__ yh,
                      float* __restrict__ cy, int rows, float extra)
{
    int r = blockIdx.x * blockDim.x + threadIdx.x;
    if (r >= rows) return;
    const float4* p = (const float4*)(src + (size_t)r * D);
    float v[D];
    float nrm = 0.f;
#pragma unroll
    for (int q = 0; q < D / 4; ++q) {
        float4 f = p[q];
        v[q * 4 + 0] = f.x; v[q * 4 + 1] = f.y; v[q * 4 + 2] = f.z; v[q * 4 + 3] = f.w;
        nrm += f.x * f.x + f.y * f.y + f.z * f.z + f.w * f.w;
    }
    cy[r] = -0.5f * LOG2E * nrm + extra;         // exact f32 norm + consts
    _Float16 hb[D];
#pragma unroll
    for (int k = 0; k < D; ++k)
        hb[k] = (_Float16)(v[k] * SQRT_LOG2E);
    f16x8* ho = (f16x8*)(yh + (size_t)r * D);
#pragma unroll
    for (int q = 0; q < D / 8; ++q) {
        f16x8 a;
#pragma unroll
        for (int e = 0; e < 8; ++e) a[e] = hb[q * 8 + e];
        ho[q] = a;
    }
}

// ---- main MFMA kernel --------------------------------------------------------
__global__ __launch_bounds__(BLOCK, 8) void kde_mfma(
    const _Float16* __restrict__ Xh, const _Float16* __restrict__ Yh,
    const float* __restrict__ cx, const float* __restrict__ cy,
    float* __restrict__ out, int jchunk)
{
    const int lane = threadIdx.x & 63;
    const int wave = threadIdx.x >> 6;
    const int i0 = (blockIdx.x * WAVES + wave) * ROWS_PER_WAVE;
    const int j0 = blockIdx.y * jchunk;
    const int fr = lane & 15;        // A-row / B-col / C-col within tile
    const int ks = (lane >> 4) * 8;  // K slice base

    f16x8 ax[WT];
#pragma unroll
    for (int t = 0; t < WT; ++t)
        ax[t] = *(const f16x8*)(Xh + (size_t)(i0 + t * 16 + fr) * D + ks);

    float rs[WT][4];
#pragma unroll
    for (int t = 0; t < WT; ++t)
#pragma unroll
        for (int r = 0; r < 4; ++r) rs[t][r] = 0.f;

    const int ntile = jchunk >> 4;   // even, >= 4 guaranteed by launch guard
    const _Float16* bp = Yh + (size_t)(j0 + fr) * D + ks;
    const float*   cyp = cy + j0 + fr;

    f16x8 bh0 = *(const f16x8*)(bp);
    float cv0 = cyp[0];
    f16x8 bh1 = *(const f16x8*)(bp + 16 * D);
    float cv1 = cyp[16];

    f32x4 acc0[WT], acc1[WT];

    for (int jt = 0; jt < ntile - 2; jt += 2) {
        // unconditional depth-2 prefetch (always in range: jt+3 <= ntile-1)
        const f16x8 nh0 = *(const f16x8*)(bp + 32 * D);
        const float nc0 = cyp[32];
        const f16x8 nh1 = *(const f16x8*)(bp + 48 * D);
        const float nc1 = cyp[48];

        {
            const f32x4 cc0 = {cv0, cv0, cv0, cv0};   // cy in MFMA C operand
#pragma unroll
            for (int t = 0; t < WT; ++t)
                acc0[t] = MFMA16F(ax[t], bh0, cc0);
        }
        {
            const f32x4 cc1 = {cv1, cv1, cv1, cv1};
#pragma unroll
            for (int t = 0; t < WT; ++t)
                acc1[t] = MFMA16F(ax[t], bh1, cc1);
        }
#pragma unroll
        for (int t = 0; t < WT; ++t)
#pragma unroll
            for (int r = 0; r < 4; ++r)
                rs[t][r] += fast_exp2(acc0[t][r]);    // VALU overlaps acc1 MFMAs
#pragma unroll
        for (int t = 0; t < WT; ++t)
#pragma unroll
            for (int r = 0; r < 4; ++r)
                rs[t][r] += fast_exp2(acc1[t][r]);

        bh0 = nh0; cv0 = nc0; bh1 = nh1; cv1 = nc1;
        bp += 32 * D; cyp += 32;
    }

    // tail: last two tiles from registers
    {
        const f32x4 cc0 = {cv0, cv0, cv0, cv0};
        const f32x4 cc1 = {cv1, cv1, cv1, cv1};
#pragma unroll
        for (int t = 0; t < WT; ++t)
            acc0[t] = MFMA16F(ax[t], bh0, cc0);
#pragma unroll
        for (int t = 0; t < WT; ++t)
            acc1[t] = MFMA16F(ax[t], bh1, cc1);
#pragma unroll
        for (int t = 0; t < WT; ++t)
#pragma unroll
            for (int r = 0; r < 4; ++r)
                rs[t][r] += fast_exp2(acc0[t][r]);
#pragma unroll
        for (int t = 0; t < WT; ++t)
#pragma unroll
            for (int r = 0; r < 4; ++r)
                rs[t][r] += fast_exp2(acc1[t][r]);
    }

    // reduce across the 16 cols (lanes sharing lane>>4)
#pragma unroll
    for (int m = 1; m < 16; m <<= 1)
#pragma unroll
        for (int t = 0; t < WT; ++t)
#pragma unroll
            for (int r = 0; r < 4; ++r)
                rs[t][r] += __shfl_xor(rs[t][r], m, 64);

    if (fr == 0) {
        const int rowbase = i0 + (lane >> 4) * 4;
#pragma unroll
        for (int t = 0; t < WT; ++t)
#pragma unroll
            for (int r = 0; r < 4; ++r) {
                const int row = rowbase + t * 16 + r;
                atomicAdd(&out[row], rs[t][r] * fast_exp2(cx[row]));
            }
    }
}

// ---- fallback: verified R1 f32 VALU kernel ----------------------------------
#define FJSPLIT 16
#define FJPER 1024
#define C16LN2PI 29.406033062549527f

__global__ __launch_bounds__(BLOCK, 2) void kde_valu(
    const float* __restrict__ X, const float* __restrict__ Y,
    float* __restrict__ out, int N, int M, float inv_n)
{
    const int tid = threadIdx.x;
    const int i   = blockIdx.x * BLOCK + tid;
    const int j0  = blockIdx.y * FJPER;
    __shared__ float cys[FJPER];
    for (int jj = tid; jj < FJPER; jj += BLOCK) {
        const float4* yv = (const float4*)(Y + (size_t)(j0 + jj) * D);
        float ny = 0.f;
#pragma unroll
        for (int q = 0; q < D / 4; ++q) {
            float4 y = yv[q];
            ny += y.x * y.x + y.y * y.y + y.z * y.z + y.w * y.w;
        }
        cys[jj] = -0.5f * ny - C16LN2PI;
    }
    __syncthreads();
    if (i >= N) return;
    float4 xv[D / 4];
    const float4* xp = (const float4*)(X + (size_t)i * D);
    float nx = 0.f;
#pragma unroll
    for (int q = 0; q < D / 4; ++q) {
        xv[q] = xp[q];
        nx += xv[q].x * xv[q].x + xv[q].y * xv[q].y + xv[q].z * xv[q].z + xv[q].w * xv[q].w;
    }
    const float cxs = -0.5f * nx;
    float acc = 0.f;
#pragma unroll 2
    for (int j = 0; j < FJPER; ++j) {
        const float4* yv = (const float4*)(Y + (size_t)(j0 + j) * D);
        float d0 = 0.f, d1 = 0.f, d2 = 0.f, d3 = 0.f;
#pragma unroll
        for (int q = 0; q < D / 4; ++q) {
            float4 y = yv[q];
            d0 = fmaf(xv[q].x, y.x, d0);
            d1 = fmaf(xv[q].y, y.y, d1);
            d2 = fmaf(xv[q].z, y.z, d2);
            d3 = fmaf(xv[q].w, y.w, d3);
        }
        acc += __expf((d0 + d1) + (d2 + d3) + cxs + cys[j]);
    }
    atomicAdd(&out[i], acc * inv_n);
}

// ---- launch ------------------------------------------------------------------
extern "C" void kernel_launch(void* const* d_in, const int* in_sizes, int n_in,
                              void* d_out, int out_size, void* d_ws, size_t ws_size,
                              hipStream_t stream) {
    (void)n_in;
    const float* X = (const float*)d_in[0];
    const float* Y = (const float*)d_in[1];
    float* out = (float*)d_out;
    const int N = in_sizes[0] / D;
    const int M = in_sizes[1] / D;

    hipMemsetAsync(d_out, 0, (size_t)out_size * sizeof(float), stream);

    const size_t xhb = (size_t)N * D * sizeof(_Float16);
    const size_t yhb = (size_t)M * D * sizeof(_Float16);
    const size_t cxb = (size_t)N * sizeof(float);
    const size_t cyb = (size_t)M * sizeof(float);
    const size_t need = xhb + yhb + cxb + cyb;

    const int jchunk = M / SPLITS;
    const int ntile = jchunk >> 4;
    const bool ok = (ws_size >= need) && (N % ROWS_PER_BLOCK == 0) &&
                    (M % (16 * SPLITS) == 0) && (ntile >= 4) && ((ntile & 1) == 0);

    if (!ok) {
        dim3 grid((N + BLOCK - 1) / BLOCK, FJSPLIT);
        kde_valu<<<grid, BLOCK, 0, stream>>>(X, Y, out, N, M, 1.0f / (float)N);
        return;
    }

    char* w = (char*)d_ws;
    _Float16* Xhp = (_Float16*)w;          w += xhb;
    _Float16* Yhp = (_Float16*)w;          w += yhb;
    float*    cxv = (float*)w;             w += cxb;
    float*    cyv = (float*)w;

    const float extraY = (float)((double)LOG2E *
        (-16.0 * log(2.0 * M_PI) - log((double)N)));

    cvt_x<<<(N + BLOCK - 1) / BLOCK, BLOCK, 0, stream>>>(X, Xhp, cxv, N);
    cvt_y<<<(M + BLOCK - 1) / BLOCK, BLOCK, 0, stream>>>(Y, Yhp, cyv, M, extraY);

    dim3 grid(N / ROWS_PER_BLOCK, SPLITS);
    kde_mfma<<<grid, BLOCK, 0, stream>>>(Xhp, Yhp, cxv, cyv, out, jchunk);
}

// Round 12
// 50.567 us; speedup vs baseline: 2.6098x; 2.6098x over previous
//
#include <hip/hip_runtime.h>
#include <math.h>

// GaussianKDE: out[i] = (1/N) * sum_j exp(x_i.y_j - 0.5||x_i||^2 - 0.5||y_j||^2 - 16*ln(2pi))
// N = M = 16384, D = 32, f32 in/out.
//
// R12 = R10 body + launch_bounds(256,4) [R10's verified codegen, VGPR=40,
// no spill] + SPLITS=64 ONLY. R11's lb(256,8) forced a register squeeze ->
// scratch spills (WRITE_SIZE 8->120MB, FETCH 4.9->52MB, 130us). But R11 also
// proved 16 blocks/CU lifts occupancy 39->71% -- so take the oversubscription
// without the squeeze.

#define D 32
#define BLOCK 256
#define WAVES 4
#define WT 4                       // 16-row i-tiles per wave
#define ROWS_PER_WAVE (WT * 16)    // 64
#define ROWS_PER_BLOCK (WAVES * ROWS_PER_WAVE)  // 256
#define SPLITS 64

#define LOG2E 1.4426950408889634f
#define SQRT_LOG2E 1.2011224087864498f

typedef __attribute__((ext_vector_type(8))) _Float16 f16x8;
typedef __attribute__((ext_vector_type(4))) float f32x4;

static __device__ __forceinline__ float fast_exp2(float x) {
    return __builtin_amdgcn_exp2f(x);   // v_exp_f32, compiler-visible (R6 fix)
}

#define MFMA16F(A, B, C) __builtin_amdgcn_mfma_f32_16x16x32_f16((A), (B), (C), 0, 0, 0)

// ---- precompute X: f16 round of sqrt(log2e)-scaled rows + cx ----------------
__global__ void cvt_x(const float* __restrict__ src, _Float16* __restrict__ hi,
                      float* __restrict__ cx, int rows)
{
    int r = blockIdx.x * blockDim.x + threadIdx.x;
    if (r >= rows) return;
    const float4* p = (const float4*)(src + (size_t)r * D);
    float v[D];
    float nrm = 0.f;
#pragma unroll
    for (int q = 0; q < D / 4; ++q) {
        float4 f = p[q];
        v[q * 4 + 0] = f.x; v[q * 4 + 1] = f.y; v[q * 4 + 2] = f.z; v[q * 4 + 3] = f.w;
        nrm += f.x * f.x + f.y * f.y + f.z * f.z + f.w * f.w;
    }
    cx[r] = -0.5f * LOG2E * nrm;                 // exact f32 norm
    _Float16 hb[D];
#pragma unroll
    for (int k = 0; k < D; ++k)
        hb[k] = (_Float16)(v[k] * SQRT_LOG2E);   // RNE
    f16x8* ho = (f16x8*)(hi + (size_t)r * D);
#pragma unroll
    for (int q = 0; q < D / 8; ++q) {
        f16x8 a;
#pragma unroll
        for (int e = 0; e < 8; ++e) a[e] = hb[q * 8 + e];
        ho[q] = a;
    }
}

// ---- precompute Y: f16 round of scaled rows + cy (log2-domain const) --------
__global__ void cvt_y(const float* __restrict__ src, _Float16* __restrict__ yh,
                      float* __restrict__ cy, int rows, float extra)
{
    int r = blockIdx.x * blockDim.x + threadIdx.x;
    if (r >= rows) return;
    const float4* p = (const float4*)(src + (size_t)r * D);
    float v[D];
    float nrm = 0.f;
#pragma unroll
    for (int q = 0; q < D / 4; ++q) {
        float4 f = p[q];
        v[q * 4 + 0] = f.x; v[q * 4 + 1] = f.y; v[q * 4 + 2] = f.z; v[q * 4 + 3] = f.w;
        nrm += f.x * f.x + f.y * f.y + f.z * f.z + f.w * f.w;
    }
    cy[r] = -0.5f * LOG2E * nrm + extra;         // exact f32 norm + consts
    _Float16 hb[D];
#pragma unroll
    for (int k = 0; k < D; ++k)
        hb[k] = (_Float16)(v[k] * SQRT_LOG2E);
    f16x8* ho = (f16x8*)(yh + (size_t)r * D);
#pragma unroll
    for (int q = 0; q < D / 8; ++q) {
        f16x8 a;
#pragma unroll
        for (int e = 0; e < 8; ++e) a[e] = hb[q * 8 + e];
        ho[q] = a;
    }
}

// ---- main MFMA kernel --------------------------------------------------------
__global__ __launch_bounds__(BLOCK, 4) void kde_mfma(
    const _Float16* __restrict__ Xh, const _Float16* __restrict__ Yh,
    const float* __restrict__ cx, const float* __restrict__ cy,
    float* __restrict__ out, int jchunk)
{
    const int lane = threadIdx.x & 63;
    const int wave = threadIdx.x >> 6;
    const int i0 = (blockIdx.x * WAVES + wave) * ROWS_PER_WAVE;
    const int j0 = blockIdx.y * jchunk;
    const int fr = lane & 15;        // A-row / B-col / C-col within tile
    const int ks = (lane >> 4) * 8;  // K slice base

    f16x8 ax[WT];
#pragma unroll
    for (int t = 0; t < WT; ++t)
        ax[t] = *(const f16x8*)(Xh + (size_t)(i0 + t * 16 + fr) * D + ks);

    float rs[WT][4];
#pragma unroll
    for (int t = 0; t < WT; ++t)
#pragma unroll
        for (int r = 0; r < 4; ++r) rs[t][r] = 0.f;

    const int ntile = jchunk >> 4;   // even, >= 4 guaranteed by launch guard
    const _Float16* bp = Yh + (size_t)(j0 + fr) * D + ks;
    const float*   cyp = cy + j0 + fr;

    f16x8 bh0 = *(const f16x8*)(bp);
    float cv0 = cyp[0];
    f16x8 bh1 = *(const f16x8*)(bp + 16 * D);
    float cv1 = cyp[16];

    f32x4 acc0[WT], acc1[WT];

    for (int jt = 0; jt < ntile - 2; jt += 2) {
        // unconditional depth-2 prefetch (always in range: jt+3 <= ntile-1)
        const f16x8 nh0 = *(const f16x8*)(bp + 32 * D);
        const float nc0 = cyp[32];
        const f16x8 nh1 = *(const f16x8*)(bp + 48 * D);
        const float nc1 = cyp[48];

        {
            const f32x4 cc0 = {cv0, cv0, cv0, cv0};   // cy in MFMA C operand
#pragma unroll
            for (int t = 0; t < WT; ++t)
                acc0[t] = MFMA16F(ax[t], bh0, cc0);
        }
        {
            const f32x4 cc1 = {cv1, cv1, cv1, cv1};
#pragma unroll
            for (int t = 0; t < WT; ++t)
                acc1[t] = MFMA16F(ax[t], bh1, cc1);
        }
#pragma unroll
        for (int t = 0; t < WT; ++t)
#pragma unroll
            for (int r = 0; r < 4; ++r)
                rs[t][r] += fast_exp2(acc0[t][r]);    // VALU overlaps acc1 MFMAs
#pragma unroll
        for (int t = 0; t < WT; ++t)
#pragma unroll
            for (int r = 0; r < 4; ++r)
                rs[t][r] += fast_exp2(acc1[t][r]);

        bh0 = nh0; cv0 = nc0; bh1 = nh1; cv1 = nc1;
        bp += 32 * D; cyp += 32;
    }

    // tail: last two tiles from registers
    {
        const f32x4 cc0 = {cv0, cv0, cv0, cv0};
        const f32x4 cc1 = {cv1, cv1, cv1, cv1};
#pragma unroll
        for (int t = 0; t < WT; ++t)
            acc0[t] = MFMA16F(ax[t], bh0, cc0);
#pragma unroll
        for (int t = 0; t < WT; ++t)
            acc1[t] = MFMA16F(ax[t], bh1, cc1);
#pragma unroll
        for (int t = 0; t < WT; ++t)
#pragma unroll
            for (int r = 0; r < 4; ++r)
                rs[t][r] += fast_exp2(acc0[t][r]);
#pragma unroll
        for (int t = 0; t < WT; ++t)
#pragma unroll
            for (int r = 0; r < 4; ++r)
                rs[t][r] += fast_exp2(acc1[t][r]);
    }

    // reduce across the 16 cols (lanes sharing lane>>4)
#pragma unroll
    for (int m = 1; m < 16; m <<= 1)
#pragma unroll
        for (int t = 0; t < WT; ++t)
#pragma unroll
            for (int r = 0; r < 4; ++r)
                rs[t][r] += __shfl_xor(rs[t][r], m, 64);

    if (fr == 0) {
        const int rowbase = i0 + (lane >> 4) * 4;
#pragma unroll
        for (int t = 0; t < WT; ++t)
#pragma unroll
            for (int r = 0; r < 4; ++r) {
                const int row = rowbase + t * 16 + r;
                atomicAdd(&out[row], rs[t][r] * fast_exp2(cx[row]));
            }
    }
}

// ---- fallback: verified R1 f32 VALU kernel ----------------------------------
#define FJSPLIT 16
#define FJPER 1024
#define C16LN2PI 29.406033062549527f

__global__ __launch_bounds__(BLOCK, 2) void kde_valu(
    const float* __restrict__ X, const float* __restrict__ Y,
    float* __restrict__ out, int N, int M, float inv_n)
{
    const int tid = threadIdx.x;
    const int i   = blockIdx.x * BLOCK + tid;
    const int j0  = blockIdx.y * FJPER;
    __shared__ float cys[FJPER];
    for (int jj = tid; jj < FJPER; jj += BLOCK) {
        const float4* yv = (const float4*)(Y + (size_t)(j0 + jj) * D);
        float ny = 0.f;
#pragma unroll
        for (int q = 0; q < D / 4; ++q) {
            float4 y = yv[q];
            ny += y.x * y.x + y.y * y.y + y.z * y.z + y.w * y.w;
        }
        cys[jj] = -0.5f * ny - C16LN2PI;
    }
    __syncthreads();
    if (i >= N) return;
    float4 xv[D / 4];
    const float4* xp = (const float4*)(X + (size_t)i * D);
    float nx = 0.f;
#pragma unroll
    for (int q = 0; q < D / 4; ++q) {
        xv[q] = xp[q];
        nx += xv[q].x * xv[q].x + xv[q].y * xv[q].y + xv[q].z * xv[q].z + xv[q].w * xv[q].w;
    }
    const float cxs = -0.5f * nx;
    float acc = 0.f;
#pragma unroll 2
    for (int j = 0; j < FJPER; ++j) {
        const float4* yv = (const float4*)(Y + (size_t)(j0 + j) * D);
        float d0 = 0.f, d1 = 0.f, d2 = 0.f, d3 = 0.f;
#pragma unroll
        for (int q = 0; q < D / 4; ++q) {
            float4 y = yv[q];
            d0 = fmaf(xv[q].x, y.x, d0);
            d1 = fmaf(xv[q].y, y.y, d1);
            d2 = fmaf(xv[q].z, y.z, d2);
            d3 = fmaf(xv[q].w, y.w, d3);
        }
        acc += __expf((d0 + d1) + (d2 + d3) + cxs + cys[j]);
    }
    atomicAdd(&out[i], acc * inv_n);
}

// ---- launch ------------------------------------------------------------------
extern "C" void kernel_launch(void* const* d_in, const int* in_sizes, int n_in,
                              void* d_out, int out_size, void* d_ws, size_t ws_size,
                              hipStream_t stream) {
    (void)n_in;
    const float* X = (const float*)d_in[0];
    const float* Y = (const float*)d_in[1];
    float* out = (float*)d_out;
    const int N = in_sizes[0] / D;
    const int M = in_sizes[1] / D;

    hipMemsetAsync(d_out, 0, (size_t)out_size * sizeof(float), stream);

    const size_t xhb = (size_t)N * D * sizeof(_Float16);
    const size_t yhb = (size_t)M * D * sizeof(_Float16);
    const size_t cxb = (size_t)N * sizeof(float);
    const size_t cyb = (size_t)M * sizeof(float);
    const size_t need = xhb + yhb + cxb + cyb;

    const int jchunk = M / SPLITS;
    const int ntile = jchunk >> 4;
    const bool ok = (ws_size >= need) && (N % ROWS_PER_BLOCK == 0) &&
                    (M % (16 * SPLITS) == 0) && (ntile >= 4) && ((ntile & 1) == 0);

    if (!ok) {
        dim3 grid((N + BLOCK - 1) / BLOCK, FJSPLIT);
        kde_valu<<<grid, BLOCK, 0, stream>>>(X, Y, out, N, M, 1.0f / (float)N);
        return;
    }

    char* w = (char*)d_ws;
    _Float16* Xhp = (_Float16*)w;          w += xhb;
    _Float16* Yhp = (_Float16*)w;          w += yhb;
    float*    cxv = (float*)w;             w += cxb;
    float*    cyv = (float*)w;

    const float extraY = (float)((double)LOG2E *
        (-16.0 * log(2.0 * M_PI) - log((double)N)));

    cvt_x<<<(N + BLOCK - 1) / BLOCK, BLOCK, 0, stream>>>(X, Xhp, cxv, N);
    cvt_y<<<(M + BLOCK - 1) / BLOCK, BLOCK, 0, stream>>>(Y, Yhp, cyv, M, extraY);

    dim3 grid(N / ROWS_PER_BLOCK, SPLITS);
    kde_mfma<<<grid, BLOCK, 0, stream>>>(Xhp, Yhp, cxv, cyv, out, jchunk);
}

// Round 13
// 49.118 us; speedup vs baseline: 2.6868x; 1.0295x over previous
//
#include <hip/hip_runtime.h>
#include <math.h>

// GaussianKDE: out[i] = (1/N) * sum_j exp(x_i.y_j - 0.5||x_i||^2 - 0.5||y_j||^2 - 16*ln(2pi))
// N = M = 16384, D = 32, f32 in/out.
//
// R13 = R10 base (SPLITS=32, lb(256,4) -- verified best grid) + ONE change:
// cy C-operand fold -> precomputed ey = 2^cy multiplier.
//   exp2(dot+cy) = exp2(dot)*ey  -->  MFMA C = single hoisted zero tuple
//   (kills 16 v_movs per j-tile), exp pass: rs = fma(exp2(acc), ey, rs).
// R12 taught: SPLITS=64 hurts (amortization+atomics); residency is bounded
// both ways. Remaining shrinkable VALU: C-init movs ~2us + cc misc ~3us.

#define D 32
#define BLOCK 256
#define WAVES 4
#define WT 4                       // 16-row i-tiles per wave
#define ROWS_PER_WAVE (WT * 16)    // 64
#define ROWS_PER_BLOCK (WAVES * ROWS_PER_WAVE)  // 256
#define SPLITS 32

#define LOG2E 1.4426950408889634f
#define SQRT_LOG2E 1.2011224087864498f

typedef __attribute__((ext_vector_type(8))) _Float16 f16x8;
typedef __attribute__((ext_vector_type(4))) float f32x4;

static __device__ __forceinline__ float fast_exp2(float x) {
    return __builtin_amdgcn_exp2f(x);   // v_exp_f32, compiler-visible (R6 fix)
}

#define MFMA16F(A, B, C) __builtin_amdgcn_mfma_f32_16x16x32_f16((A), (B), (C), 0, 0, 0)

// ---- precompute X: f16 round of sqrt(log2e)-scaled rows + cx ----------------
__global__ void cvt_x(const float* __restrict__ src, _Float16* __restrict__ hi,
                      float* __restrict__ cx, int rows)
{
    int r = blockIdx.x * blockDim.x + threadIdx.x;
    if (r >= rows) return;
    const float4* p = (const float4*)(src + (size_t)r * D);
    float v[D];
    float nrm = 0.f;
#pragma unroll
    for (int q = 0; q < D / 4; ++q) {
        float4 f = p[q];
        v[q * 4 + 0] = f.x; v[q * 4 + 1] = f.y; v[q * 4 + 2] = f.z; v[q * 4 + 3] = f.w;
        nrm += f.x * f.x + f.y * f.y + f.z * f.z + f.w * f.w;
    }
    cx[r] = -0.5f * LOG2E * nrm;                 // exact f32 norm (log2 domain)
    _Float16 hb[D];
#pragma unroll
    for (int k = 0; k < D; ++k)
        hb[k] = (_Float16)(v[k] * SQRT_LOG2E);   // RNE
    f16x8* ho = (f16x8*)(hi + (size_t)r * D);
#pragma unroll
    for (int q = 0; q < D / 8; ++q) {
        f16x8 a;
#pragma unroll
        for (int e = 0; e < 8; ++e) a[e] = hb[q * 8 + e];
        ho[q] = a;
    }
}

// ---- precompute Y: f16 round of scaled rows + ey = 2^(cy) -------------------
__global__ void cvt_y(const float* __restrict__ src, _Float16* __restrict__ yh,
                      float* __restrict__ ey, int rows, float extra)
{
    int r = blockIdx.x * blockDim.x + threadIdx.x;
    if (r >= rows) return;
    const float4* p = (const float4*)(src + (size_t)r * D);
    float v[D];
    float nrm = 0.f;
#pragma unroll
    for (int q = 0; q < D / 4; ++q) {
        float4 f = p[q];
        v[q * 4 + 0] = f.x; v[q * 4 + 1] = f.y; v[q * 4 + 2] = f.z; v[q * 4 + 3] = f.w;
        nrm += f.x * f.x + f.y * f.y + f.z * f.z + f.w * f.w;
    }
    // ey = 2^(-0.5*log2e*||y||^2 + extra); extra folds -16*log2(2pi) - log2(N)
    ey[r] = __builtin_amdgcn_exp2f(-0.5f * LOG2E * nrm + extra);
    _Float16 hb[D];
#pragma unroll
    for (int k = 0; k < D; ++k)
        hb[k] = (_Float16)(v[k] * SQRT_LOG2E);
    f16x8* ho = (f16x8*)(yh + (size_t)r * D);
#pragma unroll
    for (int q = 0; q < D / 8; ++q) {
        f16x8 a;
#pragma unroll
        for (int e = 0; e < 8; ++e) a[e] = hb[q * 8 + e];
        ho[q] = a;
    }
}

// ---- main MFMA kernel --------------------------------------------------------
__global__ __launch_bounds__(BLOCK, 4) void kde_mfma(
    const _Float16* __restrict__ Xh, const _Float16* __restrict__ Yh,
    const float* __restrict__ cx, const float* __restrict__ ey,
    float* __restrict__ out, int jchunk)
{
    const int lane = threadIdx.x & 63;
    const int wave = threadIdx.x >> 6;
    const int i0 = (blockIdx.x * WAVES + wave) * ROWS_PER_WAVE;
    const int j0 = blockIdx.y * jchunk;
    const int fr = lane & 15;        // A-row / B-col / C-col within tile
    const int ks = (lane >> 4) * 8;  // K slice base

    f16x8 ax[WT];
#pragma unroll
    for (int t = 0; t < WT; ++t)
        ax[t] = *(const f16x8*)(Xh + (size_t)(i0 + t * 16 + fr) * D + ks);

    float rs[WT][4];
#pragma unroll
    for (int t = 0; t < WT; ++t)
#pragma unroll
        for (int r = 0; r < 4; ++r) rs[t][r] = 0.f;

    const f32x4 zc = {0.f, 0.f, 0.f, 0.f};   // hoisted zero C tuple

    const int ntile = jchunk >> 4;   // even, >= 4 guaranteed by launch guard
    const _Float16* bp = Yh + (size_t)(j0 + fr) * D + ks;
    const float*   eyp = ey + j0 + fr;

    f16x8 bh0 = *(const f16x8*)(bp);
    float ev0 = eyp[0];
    f16x8 bh1 = *(const f16x8*)(bp + 16 * D);
    float ev1 = eyp[16];

    f32x4 acc0[WT], acc1[WT];

    for (int jt = 0; jt < ntile - 2; jt += 2) {
        // unconditional depth-2 prefetch (always in range: jt+3 <= ntile-1)
        const f16x8 nh0 = *(const f16x8*)(bp + 32 * D);
        const float ne0 = eyp[32];
        const f16x8 nh1 = *(const f16x8*)(bp + 48 * D);
        const float ne1 = eyp[48];

#pragma unroll
        for (int t = 0; t < WT; ++t)
            acc0[t] = MFMA16F(ax[t], bh0, zc);
#pragma unroll
        for (int t = 0; t < WT; ++t)
            acc1[t] = MFMA16F(ax[t], bh1, zc);
#pragma unroll
        for (int t = 0; t < WT; ++t)
#pragma unroll
            for (int r = 0; r < 4; ++r)
                rs[t][r] = fmaf(fast_exp2(acc0[t][r]), ev0, rs[t][r]);
#pragma unroll
        for (int t = 0; t < WT; ++t)
#pragma unroll
            for (int r = 0; r < 4; ++r)
                rs[t][r] = fmaf(fast_exp2(acc1[t][r]), ev1, rs[t][r]);

        bh0 = nh0; ev0 = ne0; bh1 = nh1; ev1 = ne1;
        bp += 32 * D; eyp += 32;
    }

    // tail: last two tiles from registers
    {
#pragma unroll
        for (int t = 0; t < WT; ++t)
            acc0[t] = MFMA16F(ax[t], bh0, zc);
#pragma unroll
        for (int t = 0; t < WT; ++t)
            acc1[t] = MFMA16F(ax[t], bh1, zc);
#pragma unroll
        for (int t = 0; t < WT; ++t)
#pragma unroll
            for (int r = 0; r < 4; ++r)
                rs[t][r] = fmaf(fast_exp2(acc0[t][r]), ev0, rs[t][r]);
#pragma unroll
        for (int t = 0; t < WT; ++t)
#pragma unroll
            for (int r = 0; r < 4; ++r)
                rs[t][r] = fmaf(fast_exp2(acc1[t][r]), ev1, rs[t][r]);
    }

    // reduce across the 16 cols (lanes sharing lane>>4)
#pragma unroll
    for (int m = 1; m < 16; m <<= 1)
#pragma unroll
        for (int t = 0; t < WT; ++t)
#pragma unroll
            for (int r = 0; r < 4; ++r)
                rs[t][r] += __shfl_xor(rs[t][r], m, 64);

    if (fr == 0) {
        const int rowbase = i0 + (lane >> 4) * 4;
#pragma unroll
        for (int t = 0; t < WT; ++t)
#pragma unroll
            for (int r = 0; r < 4; ++r) {
                const int row = rowbase + t * 16 + r;
                atomicAdd(&out[row], rs[t][r] * fast_exp2(cx[row]));
            }
    }
}

// ---- fallback: verified R1 f32 VALU kernel ----------------------------------
#define FJSPLIT 16
#define FJPER 1024
#define C16LN2PI 29.406033062549527f

__global__ __launch_bounds__(BLOCK, 2) void kde_valu(
    const float* __restrict__ X, const float* __restrict__ Y,
    float* __restrict__ out, int N, int M, float inv_n)
{
    const int tid = threadIdx.x;
    const int i   = blockIdx.x * BLOCK + tid;
    const int j0  = blockIdx.y * FJPER;
    __shared__ float cys[FJPER];
    for (int jj = tid; jj < FJPER; jj += BLOCK) {
        const float4* yv = (const float4*)(Y + (size_t)(j0 + jj) * D);
        float ny = 0.f;
#pragma unroll
        for (int q = 0; q < D / 4; ++q) {
            float4 y = yv[q];
            ny += y.x * y.x + y.y * y.y + y.z * y.z + y.w * y.w;
        }
        cys[jj] = -0.5f * ny - C16LN2PI;
    }
    __syncthreads();
    if (i >= N) return;
    float4 xv[D / 4];
    const float4* xp = (const float4*)(X + (size_t)i * D);
    float nx = 0.f;
#pragma unroll
    for (int q = 0; q < D / 4; ++q) {
        xv[q] = xp[q];
        nx += xv[q].x * xv[q].x + xv[q].y * xv[q].y + xv[q].z * xv[q].z + xv[q].w * xv[q].w;
    }
    const float cxs = -0.5f * nx;
    float acc = 0.f;
#pragma unroll 2
    for (int j = 0; j < FJPER; ++j) {
        const float4* yv = (const float4*)(Y + (size_t)(j0 + j) * D);
        float d0 = 0.f, d1 = 0.f, d2 = 0.f, d3 = 0.f;
#pragma unroll
        for (int q = 0; q < D / 4; ++q) {
            float4 y = yv[q];
            d0 = fmaf(xv[q].x, y.x, d0);
            d1 = fmaf(xv[q].y, y.y, d1);
            d2 = fmaf(xv[q].z, y.z, d2);
            d3 = fmaf(xv[q].w, y.w, d3);
        }
        acc += __expf((d0 + d1) + (d2 + d3) + cxs + cys[j]);
    }
    atomicAdd(&out[i], acc * inv_n);
}

// ---- launch ------------------------------------------------------------------
extern "C" void kernel_launch(void* const* d_in, const int* in_sizes, int n_in,
                              void* d_out, int out_size, void* d_ws, size_t ws_size,
                              hipStream_t stream) {
    (void)n_in;
    const float* X = (const float*)d_in[0];
    const float* Y = (const float*)d_in[1];
    float* out = (float*)d_out;
    const int N = in_sizes[0] / D;
    const int M = in_sizes[1] / D;

    hipMemsetAsync(d_out, 0, (size_t)out_size * sizeof(float), stream);

    const size_t xhb = (size_t)N * D * sizeof(_Float16);
    const size_t yhb = (size_t)M * D * sizeof(_Float16);
    const size_t cxb = (size_t)N * sizeof(float);
    const size_t cyb = (size_t)M * sizeof(float);
    const size_t need = xhb + yhb + cxb + cyb;

    const int jchunk = M / SPLITS;
    const int ntile = jchunk >> 4;
    const bool ok = (ws_size >= need) && (N % ROWS_PER_BLOCK == 0) &&
                    (M % (16 * SPLITS) == 0) && (ntile >= 4) && ((ntile & 1) == 0);

    if (!ok) {
        dim3 grid((N + BLOCK - 1) / BLOCK, FJSPLIT);
        kde_valu<<<grid, BLOCK, 0, stream>>>(X, Y, out, N, M, 1.0f / (float)N);
        return;
    }

    char* w = (char*)d_ws;
    _Float16* Xhp = (_Float16*)w;          w += xhb;
    _Float16* Yhp = (_Float16*)w;          w += yhb;
    float*    cxv = (float*)w;             w += cxb;
    float*    eyv = (float*)w;

    const float extraY = (float)((double)LOG2E *
        (-16.0 * log(2.0 * M_PI) - log((double)N)));

    cvt_x<<<(N + BLOCK - 1) / BLOCK, BLOCK, 0, stream>>>(X, Xhp, cxv, N);
    cvt_y<<<(M + BLOCK - 1) / BLOCK, BLOCK, 0, stream>>>(Y, Yhp, eyv, M, extraY);

    dim3 grid(N / ROWS_PER_BLOCK, SPLITS);
    kde_mfma<<<grid, BLOCK, 0, stream>>>(Xhp, Yhp, cxv, eyv, out, jchunk);
}

// Round 14
// 48.114 us; speedup vs baseline: 2.7429x; 1.0209x over previous
//
#include <hip/hip_runtime.h>
#include <math.h>

// GaussianKDE: out[i] = (1/N) * sum_j exp(x_i.y_j - 0.5||x_i||^2 - 0.5||y_j||^2 - 16*ln(2pi))
// N = M = 16384, D = 32, f32 in/out.
//
// R14 = R10 body EXACTLY (verified best, 39.9us kernel) + BLOCK 256->512
// (8 waves/WG, 4 WGs/CU). Tests the last residency axis: if the ~50% VALU
// issue-slot fill (VALUBusy 52% = exactly the computed issue work; rest idle)
// is capped by concurrent-workgroups/CU, packing 32 waves/CU into 4 WGs
// fixes it without R11's spills or R12's amortization loss.

#define D 32
#define BLOCK 512
#define WAVES 8
#define WT 4                       // 16-row i-tiles per wave
#define ROWS_PER_WAVE (WT * 16)    // 64
#define ROWS_PER_BLOCK (WAVES * ROWS_PER_WAVE)  // 512
#define SPLITS 32

#define LOG2E 1.4426950408889634f
#define SQRT_LOG2E 1.2011224087864498f

typedef __attribute__((ext_vector_type(8))) _Float16 f16x8;
typedef __attribute__((ext_vector_type(4))) float f32x4;

static __device__ __forceinline__ float fast_exp2(float x) {
    return __builtin_amdgcn_exp2f(x);   // v_exp_f32, compiler-visible (R6 fix)
}

#define MFMA16F(A, B, C) __builtin_amdgcn_mfma_f32_16x16x32_f16((A), (B), (C), 0, 0, 0)

// ---- precompute X: f16 round of sqrt(log2e)-scaled rows + cx ----------------
__global__ void cvt_x(const float* __restrict__ src, _Float16* __restrict__ hi,
                      float* __restrict__ cx, int rows)
{
    int r = blockIdx.x * blockDim.x + threadIdx.x;
    if (r >= rows) return;
    const float4* p = (const float4*)(src + (size_t)r * D);
    float v[D];
    float nrm = 0.f;
#pragma unroll
    for (int q = 0; q < D / 4; ++q) {
        float4 f = p[q];
        v[q * 4 + 0] = f.x; v[q * 4 + 1] = f.y; v[q * 4 + 2] = f.z; v[q * 4 + 3] = f.w;
        nrm += f.x * f.x + f.y * f.y + f.z * f.z + f.w * f.w;
    }
    cx[r] = -0.5f * LOG2E * nrm;                 // exact f32 norm (log2 domain)
    _Float16 hb[D];
#pragma unroll
    for (int k = 0; k < D; ++k)
        hb[k] = (_Float16)(v[k] * SQRT_LOG2E);   // RNE
    f16x8* ho = (f16x8*)(hi + (size_t)r * D);
#pragma unroll
    for (int q = 0; q < D / 8; ++q) {
        f16x8 a;
#pragma unroll
        for (int e = 0; e < 8; ++e) a[e] = hb[q * 8 + e];
        ho[q] = a;
    }
}

// ---- precompute Y: f16 round of scaled rows + cy (log2-domain const) --------
__global__ void cvt_y(const float* __restrict__ src, _Float16* __restrict__ yh,
                      float* __restrict__ cy, int rows, float extra)
{
    int r = blockIdx.x * blockDim.x + threadIdx.x;
    if (r >= rows) return;
    const float4* p = (const float4*)(src + (size_t)r * D);
    float v[D];
    float nrm = 0.f;
#pragma unroll
    for (int q = 0; q < D / 4; ++q) {
        float4 f = p[q];
        v[q * 4 + 0] = f.x; v[q * 4 + 1] = f.y; v[q * 4 + 2] = f.z; v[q * 4 + 3] = f.w;
        nrm += f.x * f.x + f.y * f.y + f.z * f.z + f.w * f.w;
    }
    cy[r] = -0.5f * LOG2E * nrm + extra;         // exact f32 norm + consts
    _Float16 hb[D];
#pragma unroll
    for (int k = 0; k < D; ++k)
        hb[k] = (_Float16)(v[k] * SQRT_LOG2E);
    f16x8* ho = (f16x8*)(yh + (size_t)r * D);
#pragma unroll
    for (int q = 0; q < D / 8; ++q) {
        f16x8 a;
#pragma unroll
        for (int e = 0; e < 8; ++e) a[e] = hb[q * 8 + e];
        ho[q] = a;
    }
}

// ---- main MFMA kernel --------------------------------------------------------
__global__ __launch_bounds__(BLOCK, 4) void kde_mfma(
    const _Float16* __restrict__ Xh, const _Float16* __restrict__ Yh,
    const float* __restrict__ cx, const float* __restrict__ cy,
    float* __restrict__ out, int jchunk)
{
    const int lane = threadIdx.x & 63;
    const int wave = threadIdx.x >> 6;
    const int i0 = (blockIdx.x * WAVES + wave) * ROWS_PER_WAVE;
    const int j0 = blockIdx.y * jchunk;
    const int fr = lane & 15;        // A-row / B-col / C-col within tile
    const int ks = (lane >> 4) * 8;  // K slice base

    f16x8 ax[WT];
#pragma unroll
    for (int t = 0; t < WT; ++t)
        ax[t] = *(const f16x8*)(Xh + (size_t)(i0 + t * 16 + fr) * D + ks);

    float rs[WT][4];
#pragma unroll
    for (int t = 0; t < WT; ++t)
#pragma unroll
        for (int r = 0; r < 4; ++r) rs[t][r] = 0.f;

    const int ntile = jchunk >> 4;   // even, >= 4 guaranteed by launch guard
    const _Float16* bp = Yh + (size_t)(j0 + fr) * D + ks;
    const float*   cyp = cy + j0 + fr;

    f16x8 bh0 = *(const f16x8*)(bp);
    float cv0 = cyp[0];
    f16x8 bh1 = *(const f16x8*)(bp + 16 * D);
    float cv1 = cyp[16];

    f32x4 acc0[WT], acc1[WT];

    for (int jt = 0; jt < ntile - 2; jt += 2) {
        // unconditional depth-2 prefetch (always in range: jt+3 <= ntile-1)
        const f16x8 nh0 = *(const f16x8*)(bp + 32 * D);
        const float nc0 = cyp[32];
        const f16x8 nh1 = *(const f16x8*)(bp + 48 * D);
        const float nc1 = cyp[48];

        {
            const f32x4 cc0 = {cv0, cv0, cv0, cv0};   // cy in MFMA C operand
#pragma unroll
            for (int t = 0; t < WT; ++t)
                acc0[t] = MFMA16F(ax[t], bh0, cc0);
        }
        {
            const f32x4 cc1 = {cv1, cv1, cv1, cv1};
#pragma unroll
            for (int t = 0; t < WT; ++t)
                acc1[t] = MFMA16F(ax[t], bh1, cc1);
        }
#pragma unroll
        for (int t = 0; t < WT; ++t)
#pragma unroll
            for (int r = 0; r < 4; ++r)
                rs[t][r] += fast_exp2(acc0[t][r]);    // VALU overlaps acc1 MFMAs
#pragma unroll
        for (int t = 0; t < WT; ++t)
#pragma unroll
            for (int r = 0; r < 4; ++r)
                rs[t][r] += fast_exp2(acc1[t][r]);

        bh0 = nh0; cv0 = nc0; bh1 = nh1; cv1 = nc1;
        bp += 32 * D; cyp += 32;
    }

    // tail: last two tiles from registers
    {
        const f32x4 cc0 = {cv0, cv0, cv0, cv0};
        const f32x4 cc1 = {cv1, cv1, cv1, cv1};
#pragma unroll
        for (int t = 0; t < WT; ++t)
            acc0[t] = MFMA16F(ax[t], bh0, cc0);
#pragma unroll
        for (int t = 0; t < WT; ++t)
            acc1[t] = MFMA16F(ax[t], bh1, cc1);
#pragma unroll
        for (int t = 0; t < WT; ++t)
#pragma unroll
            for (int r = 0; r < 4; ++r)
                rs[t][r] += fast_exp2(acc0[t][r]);
#pragma unroll
        for (int t = 0; t < WT; ++t)
#pragma unroll
            for (int r = 0; r < 4; ++r)
                rs[t][r] += fast_exp2(acc1[t][r]);
    }

    // reduce across the 16 cols (lanes sharing lane>>4)
#pragma unroll
    for (int m = 1; m < 16; m <<= 1)
#pragma unroll
        for (int t = 0; t < WT; ++t)
#pragma unroll
            for (int r = 0; r < 4; ++r)
                rs[t][r] += __shfl_xor(rs[t][r], m, 64);

    if (fr == 0) {
        const int rowbase = i0 + (lane >> 4) * 4;
#pragma unroll
        for (int t = 0; t < WT; ++t)
#pragma unroll
            for (int r = 0; r < 4; ++r) {
                const int row = rowbase + t * 16 + r;
                atomicAdd(&out[row], rs[t][r] * fast_exp2(cx[row]));
            }
    }
}

// ---- fallback: verified R1 f32 VALU kernel ----------------------------------
#define FBLOCK 256
#define FJSPLIT 16
#define FJPER 1024
#define C16LN2PI 29.406033062549527f

__global__ __launch_bounds__(FBLOCK, 2) void kde_valu(
    const float* __restrict__ X, const float* __restrict__ Y,
    float* __restrict__ out, int N, int M, float inv_n)
{
    const int tid = threadIdx.x;
    const int i   = blockIdx.x * FBLOCK + tid;
    const int j0  = blockIdx.y * FJPER;
    __shared__ float cys[FJPER];
    for (int jj = tid; jj < FJPER; jj += FBLOCK) {
        const float4* yv = (const float4*)(Y + (size_t)(j0 + jj) * D);
        float ny = 0.f;
#pragma unroll
        for (int q = 0; q < D / 4; ++q) {
            float4 y = yv[q];
            ny += y.x * y.x + y.y * y.y + y.z * y.z + y.w * y.w;
        }
        cys[jj] = -0.5f * ny - C16LN2PI;
    }
    __syncthreads();
    if (i >= N) return;
    float4 xv[D / 4];
    const float4* xp = (const float4*)(X + (size_t)i * D);
    float nx = 0.f;
#pragma unroll
    for (int q = 0; q < D / 4; ++q) {
        xv[q] = xp[q];
        nx += xv[q].x * xv[q].x + xv[q].y * xv[q].y + xv[q].z * xv[q].z + xv[q].w * xv[q].w;
    }
    const float cxs = -0.5f * nx;
    float acc = 0.f;
#pragma unroll 2
    for (int j = 0; j < FJPER; ++j) {
        const float4* yv = (const float4*)(Y + (size_t)(j0 + j) * D);
        float d0 = 0.f, d1 = 0.f, d2 = 0.f, d3 = 0.f;
#pragma unroll
        for (int q = 0; q < D / 4; ++q) {
            float4 y = yv[q];
            d0 = fmaf(xv[q].x, y.x, d0);
            d1 = fmaf(xv[q].y, y.y, d1);
            d2 = fmaf(xv[q].z, y.z, d2);
            d3 = fmaf(xv[q].w, y.w, d3);
        }
        acc += __expf((d0 + d1) + (d2 + d3) + cxs + cys[j]);
    }
    atomicAdd(&out[i], acc * inv_n);
}

// ---- launch ------------------------------------------------------------------
extern "C" void kernel_launch(void* const* d_in, const int* in_sizes, int n_in,
                              void* d_out, int out_size, void* d_ws, size_t ws_size,
                              hipStream_t stream) {
    (void)n_in;
    const float* X = (const float*)d_in[0];
    const float* Y = (const float*)d_in[1];
    float* out = (float*)d_out;
    const int N = in_sizes[0] / D;
    const int M = in_sizes[1] / D;

    hipMemsetAsync(d_out, 0, (size_t)out_size * sizeof(float), stream);

    const size_t xhb = (size_t)N * D * sizeof(_Float16);
    const size_t yhb = (size_t)M * D * sizeof(_Float16);
    const size_t cxb = (size_t)N * sizeof(float);
    const size_t cyb = (size_t)M * sizeof(float);
    const size_t need = xhb + yhb + cxb + cyb;

    const int jchunk = M / SPLITS;
    const int ntile = jchunk >> 4;
    const bool ok = (ws_size >= need) && (N % ROWS_PER_BLOCK == 0) &&
                    (M % (16 * SPLITS) == 0) && (ntile >= 4) && ((ntile & 1) == 0);

    if (!ok) {
        dim3 grid((N + FBLOCK - 1) / FBLOCK, FJSPLIT);
        kde_valu<<<grid, FBLOCK, 0, stream>>>(X, Y, out, N, M, 1.0f / (float)N);
        return;
    }

    char* w = (char*)d_ws;
    _Float16* Xhp = (_Float16*)w;          w += xhb;
    _Float16* Yhp = (_Float16*)w;          w += yhb;
    float*    cxv = (float*)w;             w += cxb;
    float*    cyv = (float*)w;

    const float extraY = (float)((double)LOG2E *
        (-16.0 * log(2.0 * M_PI) - log((double)N)));

    cvt_x<<<(N + 255) / 256, 256, 0, stream>>>(X, Xhp, cxv, N);
    cvt_y<<<(M + 255) / 256, 256, 0, stream>>>(Y, Yhp, cyv, M, extraY);

    dim3 grid(N / ROWS_PER_BLOCK, SPLITS);
    kde_mfma<<<grid, BLOCK, 0, stream>>>(Xhp, Yhp, cxv, cyv, out, jchunk);
}

// Round 15
// 47.041 us; speedup vs baseline: 2.8054x; 1.0228x over previous
//
#include <hip/hip_runtime.h>
#include <math.h>

// GaussianKDE: out[i] = (1/N) * sum_j exp(x_i.y_j - 0.5||x_i||^2 - 0.5||y_j||^2 - 16*ln(2pi))
// N = M = 16384, D = 32, f32 in/out.
//
// R15 = R10 exact body (verified best 39.9us) + prefetch depth 2->4.
// Empirical law R6-R14: wall ~= VALU_busy + MFMA_busy + ~12us const.
// R14 (guaranteed 32 waves/CU co-resident) proved the const is NOT residency.
// Last mechanism: B-load latency exposed at iter boundaries (current distance
// ~0.5-1 iter ~ L2 latency; lockstep waves stall on the same vmcnt). Depth-4
// = ~1.5 iter distance. Flat result => declare roofline at R10 config.

#define D 32
#define BLOCK 256
#define WAVES 4
#define WT 4                       // 16-row i-tiles per wave
#define ROWS_PER_WAVE (WT * 16)    // 64
#define ROWS_PER_BLOCK (WAVES * ROWS_PER_WAVE)  // 256
#define SPLITS 32

#define LOG2E 1.4426950408889634f
#define SQRT_LOG2E 1.2011224087864498f

typedef __attribute__((ext_vector_type(8))) _Float16 f16x8;
typedef __attribute__((ext_vector_type(4))) float f32x4;

static __device__ __forceinline__ float fast_exp2(float x) {
    return __builtin_amdgcn_exp2f(x);   // v_exp_f32, compiler-visible (R6 fix)
}

#define MFMA16F(A, B, C) __builtin_amdgcn_mfma_f32_16x16x32_f16((A), (B), (C), 0, 0, 0)

// ---- precompute X: f16 round of sqrt(log2e)-scaled rows + cx ----------------
__global__ void cvt_x(const float* __restrict__ src, _Float16* __restrict__ hi,
                      float* __restrict__ cx, int rows)
{
    int r = blockIdx.x * blockDim.x + threadIdx.x;
    if (r >= rows) return;
    const float4* p = (const float4*)(src + (size_t)r * D);
    float v[D];
    float nrm = 0.f;
#pragma unroll
    for (int q = 0; q < D / 4; ++q) {
        float4 f = p[q];
        v[q * 4 + 0] = f.x; v[q * 4 + 1] = f.y; v[q * 4 + 2] = f.z; v[q * 4 + 3] = f.w;
        nrm += f.x * f.x + f.y * f.y + f.z * f.z + f.w * f.w;
    }
    cx[r] = -0.5f * LOG2E * nrm;                 // exact f32 norm (log2 domain)
    _Float16 hb[D];
#pragma unroll
    for (int k = 0; k < D; ++k)
        hb[k] = (_Float16)(v[k] * SQRT_LOG2E);   // RNE
    f16x8* ho = (f16x8*)(hi + (size_t)r * D);
#pragma unroll
    for (int q = 0; q < D / 8; ++q) {
        f16x8 a;
#pragma unroll
        for (int e = 0; e < 8; ++e) a[e] = hb[q * 8 + e];
        ho[q] = a;
    }
}

// ---- precompute Y: f16 round of scaled rows + cy (log2-domain const) --------
__global__ void cvt_y(const float* __restrict__ src, _Float16* __restrict__ yh,
                      float* __restrict__ cy, int rows, float extra)
{
    int r = blockIdx.x * blockDim.x + threadIdx.x;
    if (r >= rows) return;
    const float4* p = (const float4*)(src + (size_t)r * D);
    float v[D];
    float nrm = 0.f;
#pragma unroll
    for (int q = 0; q < D / 4; ++q) {
        float4 f = p[q];
        v[q * 4 + 0] = f.x; v[q * 4 + 1] = f.y; v[q * 4 + 2] = f.z; v[q * 4 + 3] = f.w;
        nrm += f.x * f.x + f.y * f.y + f.z * f.z + f.w * f.w;
    }
    cy[r] = -0.5f * LOG2E * nrm + extra;         // exact f32 norm + consts
    _Float16 hb[D];
#pragma unroll
    for (int k = 0; k < D; ++k)
        hb[k] = (_Float16)(v[k] * SQRT_LOG2E);
    f16x8* ho = (f16x8*)(yh + (size_t)r * D);
#pragma unroll
    for (int q = 0; q < D / 8; ++q) {
        f16x8 a;
#pragma unroll
        for (int e = 0; e < 8; ++e) a[e] = hb[q * 8 + e];
        ho[q] = a;
    }
}

// ---- main MFMA kernel --------------------------------------------------------
__global__ __launch_bounds__(BLOCK, 4) void kde_mfma(
    const _Float16* __restrict__ Xh, const _Float16* __restrict__ Yh,
    const float* __restrict__ cx, const float* __restrict__ cy,
    float* __restrict__ out, int jchunk)
{
    const int lane = threadIdx.x & 63;
    const int wave = threadIdx.x >> 6;
    const int i0 = (blockIdx.x * WAVES + wave) * ROWS_PER_WAVE;
    const int j0 = blockIdx.y * jchunk;
    const int fr = lane & 15;        // A-row / B-col / C-col within tile
    const int ks = (lane >> 4) * 8;  // K slice base

    f16x8 ax[WT];
#pragma unroll
    for (int t = 0; t < WT; ++t)
        ax[t] = *(const f16x8*)(Xh + (size_t)(i0 + t * 16 + fr) * D + ks);

    float rs[WT][4];
#pragma unroll
    for (int t = 0; t < WT; ++t)
#pragma unroll
        for (int r = 0; r < 4; ++r) rs[t][r] = 0.f;

    const int ntile = jchunk >> 4;   // ntile >= 8, ntile % 4 == 0 (launch guard)
    const _Float16* bp = Yh + (size_t)(j0 + fr) * D + ks;
    const float*   cyp = cy + j0 + fr;

#define LD_BH(T) (*(const f16x8*)(bp + (size_t)(T) * (16 * D)))
#define LD_CY(T) (cyp[(T) * 16])

    // depth-4 pipeline: pairs A = {jt, jt+1}, B = {jt+2, jt+3}
    f16x8 a0 = LD_BH(0), a1 = LD_BH(1), b0 = LD_BH(2), b1 = LD_BH(3);
    float ca0 = LD_CY(0), ca1 = LD_CY(1), cb0 = LD_CY(2), cb1 = LD_CY(3);

    f32x4 acc0[WT], acc1[WT];

#define KDE_PAIR(BH0, BH1, CV0, CV1)                                            \
    do {                                                                        \
        {                                                                       \
            const f32x4 cc0 = {(CV0), (CV0), (CV0), (CV0)};                     \
            _Pragma("unroll")                                                   \
            for (int t = 0; t < WT; ++t)                                        \
                acc0[t] = MFMA16F(ax[t], (BH0), cc0);                           \
        }                                                                       \
        {                                                                       \
            const f32x4 cc1 = {(CV1), (CV1), (CV1), (CV1)};                     \
            _Pragma("unroll")                                                   \
            for (int t = 0; t < WT; ++t)                                        \
                acc1[t] = MFMA16F(ax[t], (BH1), cc1);                           \
        }                                                                       \
        _Pragma("unroll")                                                       \
        for (int t = 0; t < WT; ++t)                                            \
            _Pragma("unroll")                                                   \
            for (int r = 0; r < 4; ++r)                                         \
                rs[t][r] += fast_exp2(acc0[t][r]);                              \
        _Pragma("unroll")                                                       \
        for (int t = 0; t < WT; ++t)                                            \
            _Pragma("unroll")                                                   \
            for (int r = 0; r < 4; ++r)                                         \
                rs[t][r] += fast_exp2(acc1[t][r]);                              \
    } while (0)

    for (int jt = 0; jt + 8 <= ntile; jt += 4) {
        // prefetch next A-pair (tiles jt+4, jt+5) -- used NEXT iteration
        const f16x8 n0 = LD_BH(jt + 4), n1 = LD_BH(jt + 5);
        const float m0 = LD_CY(jt + 4), m1 = LD_CY(jt + 5);

        KDE_PAIR(a0, a1, ca0, ca1);                   // compute tiles jt, jt+1

        // prefetch next B-pair (tiles jt+6, jt+7)
        const f16x8 n2 = LD_BH(jt + 6), n3 = LD_BH(jt + 7);
        const float m2 = LD_CY(jt + 6), m3 = LD_CY(jt + 7);

        KDE_PAIR(b0, b1, cb0, cb1);                   // compute tiles jt+2, jt+3

        a0 = n0; a1 = n1; ca0 = m0; ca1 = m1;
        b0 = n2; b1 = n3; cb0 = m2; cb1 = m3;
    }
    // tail: last 4 tiles, all in registers
    KDE_PAIR(a0, a1, ca0, ca1);
    KDE_PAIR(b0, b1, cb0, cb1);
#undef KDE_PAIR
#undef LD_BH
#undef LD_CY

    // reduce across the 16 cols (lanes sharing lane>>4)
#pragma unroll
    for (int m = 1; m < 16; m <<= 1)
#pragma unroll
        for (int t = 0; t < WT; ++t)
#pragma unroll
            for (int r = 0; r < 4; ++r)
                rs[t][r] += __shfl_xor(rs[t][r], m, 64);

    if (fr == 0) {
        const int rowbase = i0 + (lane >> 4) * 4;
#pragma unroll
        for (int t = 0; t < WT; ++t)
#pragma unroll
            for (int r = 0; r < 4; ++r) {
                const int row = rowbase + t * 16 + r;
                atomicAdd(&out[row], rs[t][r] * fast_exp2(cx[row]));
            }
    }
}

// ---- fallback: verified R1 f32 VALU kernel ----------------------------------
#define FBLOCK 256
#define FJSPLIT 16
#define FJPER 1024
#define C16LN2PI 29.406033062549527f

__global__ __launch_bounds__(FBLOCK, 2) void kde_valu(
    const float* __restrict__ X, const float* __restrict__ Y,
    float* __restrict__ out, int N, int M, float inv_n)
{
    const int tid = threadIdx.x;
    const int i   = blockIdx.x * FBLOCK + tid;
    const int j0  = blockIdx.y * FJPER;
    __shared__ float cys[FJPER];
    for (int jj = tid; jj < FJPER; jj += FBLOCK) {
        const float4* yv = (const float4*)(Y + (size_t)(j0 + jj) * D);
        float ny = 0.f;
#pragma unroll
        for (int q = 0; q < D / 4; ++q) {
            float4 y = yv[q];
            ny += y.x * y.x + y.y * y.y + y.z * y.z + y.w * y.w;
        }
        cys[jj] = -0.5f * ny - C16LN2PI;
    }
    __syncthreads();
    if (i >= N) return;
    float4 xv[D / 4];
    const float4* xp = (const float4*)(X + (size_t)i * D);
    float nx = 0.f;
#pragma unroll
    for (int q = 0; q < D / 4; ++q) {
        xv[q] = xp[q];
        nx += xv[q].x * xv[q].x + xv[q].y * xv[q].y + xv[q].z * xv[q].z + xv[q].w * xv[q].w;
    }
    const float cxs = -0.5f * nx;
    float acc = 0.f;
#pragma unroll 2
    for (int j = 0; j < FJPER; ++j) {
        const float4* yv = (const float4*)(Y + (size_t)(j0 + j) * D);
        float d0 = 0.f, d1 = 0.f, d2 = 0.f, d3 = 0.f;
#pragma unroll
        for (int q = 0; q < D / 4; ++q) {
            float4 y = yv[q];
            d0 = fmaf(xv[q].x, y.x, d0);
            d1 = fmaf(xv[q].y, y.y, d1);
            d2 = fmaf(xv[q].z, y.z, d2);
            d3 = fmaf(xv[q].w, y.w, d3);
        }
        acc += __expf((d0 + d1) + (d2 + d3) + cxs + cys[j]);
    }
    atomicAdd(&out[i], acc * inv_n);
}

// ---- launch ------------------------------------------------------------------
extern "C" void kernel_launch(void* const* d_in, const int* in_sizes, int n_in,
                              void* d_out, int out_size, void* d_ws, size_t ws_size,
                              hipStream_t stream) {
    (void)n_in;
    const float* X = (const float*)d_in[0];
    const float* Y = (const float*)d_in[1];
    float* out = (float*)d_out;
    const int N = in_sizes[0] / D;
    const int M = in_sizes[1] / D;

    hipMemsetAsync(d_out, 0, (size_t)out_size * sizeof(float), stream);

    const size_t xhb = (size_t)N * D * sizeof(_Float16);
    const size_t yhb = (size_t)M * D * sizeof(_Float16);
    const size_t cxb = (size_t)N * sizeof(float);
    const size_t cyb = (size_t)M * sizeof(float);
    const size_t need = xhb + yhb + cxb + cyb;

    const int jchunk = M / SPLITS;
    const int ntile = jchunk >> 4;
    const bool ok = (ws_size >= need) && (N % ROWS_PER_BLOCK == 0) &&
                    (M % (16 * SPLITS) == 0) && (ntile >= 8) && ((ntile & 3) == 0);

    if (!ok) {
        dim3 grid((N + FBLOCK - 1) / FBLOCK, FJSPLIT);
        kde_valu<<<grid, FBLOCK, 0, stream>>>(X, Y, out, N, M, 1.0f / (float)N);
        return;
    }

    char* w = (char*)d_ws;
    _Float16* Xhp = (_Float16*)w;          w += xhb;
    _Float16* Yhp = (_Float16*)w;          w += yhb;
    float*    cxv = (float*)w;             w += cxb;
    float*    cyv = (float*)w;

    const float extraY = (float)((double)LOG2E *
        (-16.0 * log(2.0 * M_PI) - log((double)N)));

    cvt_x<<<(N + 255) / 256, 256, 0, stream>>>(X, Xhp, cxv, N);
    cvt_y<<<(M + 255) / 256, 256, 0, stream>>>(Y, Yhp, cyv, M, extraY);

    dim3 grid(N / ROWS_PER_BLOCK, SPLITS);
    kde_mfma<<<grid, BLOCK, 0, stream>>>(Xhp, Yhp, cxv, cyv, out, jchunk);
}